// Round 1
// 426.842 us; speedup vs baseline: 1.0153x; 1.0153x over previous
//
#include <hip/hip_runtime.h>
#include <hip/hip_fp16.h>

typedef __attribute__((ext_vector_type(4))) float f32x4;
typedef __attribute__((ext_vector_type(8))) short s16x8;
typedef __attribute__((ext_vector_type(4))) short s16x4;
typedef unsigned short u16;
typedef unsigned int u32;

__device__ __forceinline__ u16 f2bf(float f) {
    union { float f; unsigned u; } x; x.f = f;
    return (u16)((x.u + 0x7fffu + ((x.u >> 16) & 1u)) >> 16);
}

__device__ __forceinline__ void ld16(const void* g, void* l) {
    __builtin_amdgcn_global_load_lds(
        (const __attribute__((address_space(1))) unsigned int*)g,
        (__attribute__((address_space(3))) unsigned int*)l, 16, 0, 0);
}

// ---------------------------------------------------------------------------
// BK=64 K-step of a 128x256 output tile (legacy 2-barrier core, still used by
// sgemm_causal and pv_gemm this round).
// ---------------------------------------------------------------------------
__device__ __forceinline__ void kstep64(const u16* gA, const u16* gB, const u16* gC,
                                        long lda, long ldb,
                                        u16* sA, u16* sB,
                                        int wm, int wn, int lm, int lg,
                                        f32x4 acc0[4][4], f32x4 acc1[4][4])
{
    const int t = threadIdx.x;
    __syncthreads();                 // previous iter's readers done
#pragma unroll
    for (int p = 0; p < 4; p++) {
        ld16(gA + (long)p * 32 * lda, sA + p * 2048 + t * 8);
        ld16(gB + (long)p * 32 * ldb, sB + p * 2048 + t * 8);
        ld16(gC + (long)p * 32 * ldb, sB + 8192 + p * 2048 + t * 8);
    }
    __syncthreads();                 // drains vmcnt for global_load_lds

#pragma unroll
    for (int s = 0; s < 2; s++) {
        s16x8 af[4], bf[4], cf[4];
        const int co = (((s * 4 + lg) ^ (lm & 7)) << 3);
#pragma unroll
        for (int i = 0; i < 4; i++) {
            af[i] = *(const s16x8*)&sA[(wm + i * 16 + lm) * 64 + co];
            bf[i] = *(const s16x8*)&sB[(wn + i * 16 + lm) * 64 + co];
            cf[i] = *(const s16x8*)&sB[8192 + (wn + i * 16 + lm) * 64 + co];
        }
#pragma unroll
        for (int i = 0; i < 4; i++)
#pragma unroll
            for (int j = 0; j < 4; j++) {
                acc0[i][j] = __builtin_amdgcn_mfma_f32_16x16x32_bf16(af[i], bf[j], acc0[i][j], 0, 0, 0);
                acc1[i][j] = __builtin_amdgcn_mfma_f32_16x16x32_bf16(af[i], cf[j], acc1[i][j], 0, 0, 0);
            }
    }
}

// Contiguous-K core: C[m][n] = sum_k A[m][k]*B[n][k] for n in two 128-tiles.
__device__ __forceinline__ void gemm_core64(const u16* A, long lda,
                                            const u16* B0, const u16* B1, long ldb,
                                            int m0, int kEnd,
                                            f32x4 acc0[4][4], f32x4 acc1[4][4],
                                            u16* sA, u16* sB)
{
    const int t    = threadIdx.x;
    const int lane = t & 63;
    const int wave = t >> 6;
    const int wm   = (wave & 1) << 6;
    const int wn   = (wave >> 1) << 6;
    const int lm   = lane & 15;
    const int lg   = lane >> 4;
    const int sr   = t >> 3;                              // staging row 0..31
    const int sc   = (((t & 7) ^ ((t >> 3) & 7)) << 3);   // swizzled chunk
    const u16* gA0 = A + (long)(m0 + sr) * lda + sc;
    const u16* gB0 = B0 + (long)sr * ldb + sc;
    const u16* gC0 = B1 + (long)sr * ldb + sc;

    for (int k0 = 0; k0 < kEnd; k0 += 64)
        kstep64(gA0 + k0, gB0 + k0, gC0 + k0, lda, ldb,
                sA, sB, wm, wn, lm, lg, acc0, acc1);
}

// ---------------------------------------------------------------------------
// Conversions
// ---------------------------------------------------------------------------
__global__ void convert_x(const float* __restrict__ X, u16* __restrict__ Xb) {
    long idx = ((long)blockIdx.x * 256 + threadIdx.x) * 4;
    f32x4 v = *(const f32x4*)&X[idx];
    s16x4 o;
    o.x = (short)f2bf(v.x); o.y = (short)f2bf(v.y);
    o.z = (short)f2bf(v.z); o.w = (short)f2bf(v.w);
    *(s16x4*)&Xb[idx] = o;
}

// W[k][n] fp32 -> Wt[n][k] bf16, 64x64 LDS tile transpose. grid (256, 3)
__global__ void convert_w(const float* __restrict__ Wk, const float* __restrict__ Wq,
                          const float* __restrict__ Wv,
                          u16* __restrict__ Wkt, u16* __restrict__ Wqt, u16* __restrict__ Wvt) {
    const float* W; u16* O;
    if (blockIdx.y == 0)      { W = Wk; O = Wkt; }
    else if (blockIdx.y == 1) { W = Wq; O = Wqt; }
    else                      { W = Wv; O = Wvt; }
    __shared__ u16 tile[64][65];
    int k0 = (blockIdx.x >> 4) << 6, n0 = (blockIdx.x & 15) << 6;
    int t = threadIdx.x;
    int rr = t >> 4, cc = (t & 15) << 2;
#pragma unroll
    for (int i = 0; i < 4; i++) {
        int row = rr + i * 16;
        f32x4 v = *(const f32x4*)&W[(long)(k0 + row) * 1024 + n0 + cc];
        tile[row][cc + 0] = f2bf(v.x); tile[row][cc + 1] = f2bf(v.y);
        tile[row][cc + 2] = f2bf(v.z); tile[row][cc + 3] = f2bf(v.w);
    }
    __syncthreads();
#pragma unroll
    for (int i = 0; i < 4; i++) {
        int row = rr + i * 16;
        s16x4 pk;
        pk.x = (short)tile[cc + 0][row]; pk.y = (short)tile[cc + 1][row];
        pk.z = (short)tile[cc + 2][row]; pk.w = (short)tile[cc + 3][row];
        *(s16x4*)&O[(long)(n0 + row) * 1024 + k0 + cc] = pk;
    }
}

// ---------------------------------------------------------------------------
// 8-phase 256x256 projection GEMM (T2+T3+T4+T5 per the verified template).
// 512 threads = 8 waves (2M x 4N), per-wave output 128x64, BK=64, LDS 128 KiB
// double-buffer. Counted vmcnt(6) — loads stay 3 half-tiles in flight across
// barriers; never drained to 0 in the main loop.
//
// Stage stream (iteration computes tile E=2it from buf0 @ph0-3, O=2it+1 from
// buf1 @ph4-7; stages one half-tile per phase):
//   ph0: O.A1   ph1: E'.B0  ph2: E'.B1  ph3: E'.A0
//   ph4: E'.A1  ph5: O'.B0  ph6: O'.B1  ph7: O'.A0     (E'=2it+2, O'=2it+3)
// ds_read distribution per tile: ph+0: A-lo(8)+B-all(8); ph+2: A-hi(8).
// Slot-freedom proof: B slots last read @ph+0 -> free @ph+1 (E'.B0@1 OK);
// A slots last read @ph+2 -> free @ph+3 (E'.A0@3, E'.A1@4 OK); buf1 B free
// @5, buf1 A free @7 (O'.A0@7, O.A1@0 OK). Every overwrite is separated from
// its last reader by that phase's lgkmcnt(0) + end-of-phase s_barrier.
// vmcnt proof: before ph4 reads of O (staged @prev5,6,7 + @0), newer stages
// are @1,2,3 = 6 loads -> vmcnt(6). Before next ph0 reads of E' (staged
// @1,2,3,4), newer are @5,6,7 = 6 loads -> vmcnt(6). Last iteration stages
// nothing for tiles 16/17, so the ph3 wait must be vmcnt(0) to cover O.A1.
// ---------------------------------------------------------------------------
__device__ __forceinline__ void stage_half64(const u16* gbase, u16* lbase,
                                             int kt, int h, int t) {
    // gbase: per-thread global base (row sr, swizzled chunk sc), row stride 1024
    const u16* g = gbase + (long)(h * 128) * 1024 + kt * 64;
    u16* l = lbase + h * 8192 + t * 8;
    ld16(g, l);
    ld16(g + 64 * 1024, l + 4096);
}

__device__ __forceinline__ void read_A8(const u16* sA, int arow, int ih,
                                        int co0, int co1, s16x8 af[4][2]) {
#pragma unroll
    for (int i = 0; i < 4; i++) {
        af[i][0] = *(const s16x8*)&sA[(arow + (ih * 4 + i) * 16) * 64 + co0];
        af[i][1] = *(const s16x8*)&sA[(arow + (ih * 4 + i) * 16) * 64 + co1];
    }
}

__device__ __forceinline__ void read_B8(const u16* sB, int brow,
                                        int co0, int co1, s16x8 bf[4][2]) {
#pragma unroll
    for (int j = 0; j < 4; j++) {
        bf[j][0] = *(const s16x8*)&sB[(brow + j * 16) * 64 + co0];
        bf[j][1] = *(const s16x8*)&sB[(brow + j * 16) * 64 + co1];
    }
}

__device__ __forceinline__ void mfma16q(f32x4 acc[8][4], const s16x8 af[4][2],
                                        const s16x8 bf[4][2], int ih, int jh) {
    __builtin_amdgcn_s_setprio(1);
#pragma unroll
    for (int i = 0; i < 4; i++)
#pragma unroll
        for (int j = 0; j < 2; j++)
#pragma unroll
            for (int s = 0; s < 2; s++)
                acc[ih * 4 + i][jh * 2 + j] = __builtin_amdgcn_mfma_f32_16x16x32_bf16(
                    af[i][s], bf[jh * 2 + j][s], acc[ih * 4 + i][jh * 2 + j], 0, 0, 0);
    __builtin_amdgcn_s_setprio(0);
}

#define PH_BAR()  __builtin_amdgcn_s_barrier()
#define PH_LGKM() asm volatile("s_waitcnt lgkmcnt(0)" ::: "memory")

__global__ __launch_bounds__(512, 2) void proj_all8(const u16* __restrict__ X,
                                                    const u16* __restrict__ Wqt,
                                                    const u16* __restrict__ Wkt,
                                                    const u16* __restrict__ Wvt,
                                                    u16* __restrict__ Qb,
                                                    u16* __restrict__ Kb,
                                                    u16* __restrict__ Vt) {
    __shared__ u16 lds[65536];                   // 128 KiB: A bufs then B bufs
    const int bx  = blockIdx.x;
    const int z   = bx >> 8;                     // 0:Q 1:K 2:V (grid 768)
    const int rem = bx & 255;
    const int m0  = (rem >> 2) << 8;
    const int n0  = (rem & 3) << 8;
    const u16* Wt = (z == 0) ? Wqt : (z == 1) ? Wkt : Wvt;

    const int t  = threadIdx.x;
    const int sr = t >> 3;                       // staging row 0..63
    const int sc = ((t & 7) ^ (sr & 7)) << 3;    // swizzled 16B chunk (u16 units)
    const u16* Ast = X  + (long)(m0 + sr) * 1024 + sc;
    const u16* Bst = Wt + (long)(n0 + sr) * 1024 + sc;
    u16* sA0 = lds;
    u16* sA1 = lds + 16384;
    u16* sB0 = lds + 32768;
    u16* sB1 = lds + 49152;

    const int lane = t & 63, w = t >> 6;
    const int wr = w >> 2, wc = w & 3;           // 2M x 4N wave grid
    const int lm = lane & 15, lg = lane >> 4;
    const int arow = wr * 128 + lm;
    const int brow = wc * 64 + lm;
    const int co0 = ((lg) ^ (lm & 7)) << 3;      // k-chunk for s=0 (swizzled)
    const int co1 = ((4 + lg) ^ (lm & 7)) << 3;  // k-chunk for s=1

    f32x4 acc[8][4] = {};
    s16x8 af[4][2], bf[4][2];

    // Prologue: tile0 {B0,B1,A0,A1} + tile1 {B0,B1,A0} (oldest-first order
    // matches steady-state vmcnt accounting). 14 loads; wait until only
    // tile1's 3 halves (6 loads) remain in flight.
    stage_half64(Bst, sB0, 0, 0, t); stage_half64(Bst, sB0, 0, 1, t);
    stage_half64(Ast, sA0, 0, 0, t); stage_half64(Ast, sA0, 0, 1, t);
    stage_half64(Bst, sB1, 1, 0, t); stage_half64(Bst, sB1, 1, 1, t);
    stage_half64(Ast, sA1, 1, 0, t);
    asm volatile("s_waitcnt vmcnt(6)" ::: "memory");
    PH_BAR();

#pragma unroll 1
    for (int it = 0; it < 8; it++) {
        const int  tO   = 2 * it + 1;
        const bool more = (it < 7);
        // ---- phase 0: E quad (lo,lo); reads A-lo + B-all; stage O.A1
        read_A8(sA0, arow, 0, co0, co1, af);
        read_B8(sB0, brow, co0, co1, bf);
        stage_half64(Ast, sA1, tO, 1, t);
        PH_BAR(); PH_LGKM();
        mfma16q(acc, af, bf, 0, 0);
        PH_BAR();
        // ---- phase 1: E quad (lo,hi); stage E'.B0
        if (more) stage_half64(Bst, sB0, tO + 1, 0, t);
        PH_BAR(); PH_LGKM();
        mfma16q(acc, af, bf, 0, 1);
        PH_BAR();
        // ---- phase 2: E quad (hi,lo); reads A-hi; stage E'.B1
        read_A8(sA0, arow, 1, co0, co1, af);
        if (more) stage_half64(Bst, sB0, tO + 1, 1, t);
        PH_BAR(); PH_LGKM();
        mfma16q(acc, af, bf, 1, 0);
        PH_BAR();
        // ---- phase 3: E quad (hi,hi); stage E'.A0; counted vmcnt
        if (more) stage_half64(Ast, sA0, tO + 1, 0, t);
        PH_BAR(); PH_LGKM();
        mfma16q(acc, af, bf, 1, 1);
        if (more) asm volatile("s_waitcnt vmcnt(6)" ::: "memory");
        else      asm volatile("s_waitcnt vmcnt(0)" ::: "memory");
        PH_BAR();
        // ---- phase 4: O quad (lo,lo); reads A-lo + B-all; stage E'.A1
        read_A8(sA1, arow, 0, co0, co1, af);
        read_B8(sB1, brow, co0, co1, bf);
        if (more) stage_half64(Ast, sA0, tO + 1, 1, t);
        PH_BAR(); PH_LGKM();
        mfma16q(acc, af, bf, 0, 0);
        PH_BAR();
        // ---- phase 5: O quad (lo,hi); stage O'.B0
        if (more) stage_half64(Bst, sB1, tO + 2, 0, t);
        PH_BAR(); PH_LGKM();
        mfma16q(acc, af, bf, 0, 1);
        PH_BAR();
        // ---- phase 6: O quad (hi,lo); reads A-hi; stage O'.B1
        read_A8(sA1, arow, 1, co0, co1, af);
        if (more) stage_half64(Bst, sB1, tO + 2, 1, t);
        PH_BAR(); PH_LGKM();
        mfma16q(acc, af, bf, 1, 0);
        PH_BAR();
        // ---- phase 7: O quad (hi,hi); stage O'.A0; counted vmcnt
        if (more) stage_half64(Ast, sA1, tO + 2, 0, t);
        PH_BAR(); PH_LGKM();
        mfma16q(acc, af, bf, 1, 1);
        if (more) asm volatile("s_waitcnt vmcnt(6)" ::: "memory");
        PH_BAR();
    }

    // Epilogue: rows m0 + wr*128 + i*16 + lg*4 + r ; cols n0 + wc*64 + j*16 + lm
    if (z < 2) {
        u16* O = (z == 0) ? Qb : Kb;
#pragma unroll
        for (int i = 0; i < 8; i++)
#pragma unroll
            for (int j = 0; j < 4; j++)
#pragma unroll
                for (int r = 0; r < 4; r++) {
                    int row = m0 + wr * 128 + i * 16 + lg * 4 + r;
                    int col = n0 + wc * 64 + j * 16 + lm;
                    O[(long)row * 1024 + col] = f2bf(acc[i][j][r]);
                }
    } else {
#pragma unroll
        for (int i = 0; i < 8; i++)
#pragma unroll
            for (int j = 0; j < 4; j++) {
                int row0 = m0 + wr * 128 + i * 16 + lg * 4;
                int col  = n0 + wc * 64 + j * 16 + lm;
                int b = row0 >> 12, s = row0 & 4095;
                s16x4 p0;
                p0.x = (short)f2bf(acc[i][j][0]); p0.y = (short)f2bf(acc[i][j][1]);
                p0.z = (short)f2bf(acc[i][j][2]); p0.w = (short)f2bf(acc[i][j][3]);
                *(s16x4*)&Vt[(long)b * 4194304 + (long)col * 4096 + s] = p0;
            }
    }
}

// ---------------------------------------------------------------------------
// Fused S-GEMM + softmax-numerator: P = exp(QK^T/32 - 16) (causal; fixed
// offset replaces the row max — scale-invariant, cancels in p/l). P written
// bf16 into packed lower-tri tiles; per-row sums accumulated into l[] via
// 16-lane shuffle reduction + one atomicAdd per row-quarter. grid 4*272.
// ---------------------------------------------------------------------------
__global__ __launch_bounds__(256, 2) void sgemm_causal(const u16* __restrict__ Q,
                                                       const u16* __restrict__ K,
                                                       u16* __restrict__ S,
                                                       float* __restrict__ l) {
    __shared__ u16 sA[8192], sB[16384];
    int b  = blockIdx.x / 272;
    int tt = blockIdx.x % 272;
    int it = (int)(2.0f * sqrtf((float)tt + 1.0f)) - 1;
    if (it > 31) it = 31;
    if (it < 0) it = 0;
    while (it < 31 && (((it + 2) * (it + 2)) >> 2) <= tt) ++it;
    while (it > 0 && (((it + 1) * (it + 1)) >> 2) > tt) --it;
    int jp  = tt - (((it + 1) * (it + 1)) >> 2);
    int jt0 = jp * 2, jt1 = jt0 + 1;
    bool valid1 = (jt1 <= it);

    const u16* A  = Q + (long)b * 4194304;
    const u16* Kp = K + (long)b * 4194304;
    f32x4 acc0[4][4] = {}, acc1[4][4] = {};
    gemm_core64(A, 1024, Kp + (long)jt0 * 131072, Kp + (long)jt1 * 131072, 1024,
                it * 128, 1024, acc0, acc1, sA, sB);

    long tribase = (long)(b * 528 + ((it * (it + 1)) >> 1));
    u16* Sp0 = S + (tribase + jt0) * 16384;
    u16* Sp1 = S + (tribase + jt1) * 16384;
    int lane = threadIdx.x & 63, wave = threadIdx.x >> 6;
    int wm = (wave & 1) << 6, wn = (wave >> 1) << 6, lm = lane & 15, lg = lane >> 4;
    const float LOG2E = 1.44269504088896f;

    float rs[4][4];
#pragma unroll
    for (int i = 0; i < 4; i++)
#pragma unroll
        for (int r = 0; r < 4; r++) rs[i][r] = 0.0f;

#pragma unroll
    for (int i = 0; i < 4; i++)
#pragma unroll
        for (int j = 0; j < 4; j++)
#pragma unroll
            for (int r = 0; r < 4; r++) {
                int ri = wm + i * 16 + lg * 4 + r;
                int cj = wn + j * 16 + lm;
                int gi = it * 128 + ri;
                float p0 = (jt0 * 128 + cj > gi) ? 0.0f
                         : exp2f((acc0[i][j][r] * 0.03125f - 16.0f) * LOG2E);
                Sp0[ri * 128 + cj] = f2bf(p0);
                rs[i][r] += p0;
                if (valid1) {
                    float p1 = (jt1 * 128 + cj > gi) ? 0.0f
                             : exp2f((acc1[i][j][r] * 0.03125f - 16.0f) * LOG2E);
                    Sp1[ri * 128 + cj] = f2bf(p1);
                    rs[i][r] += p1;
                }
            }

#pragma unroll
    for (int i = 0; i < 4; i++)
#pragma unroll
        for (int r = 0; r < 4; r++) {
            float s = rs[i][r];
            s += __shfl_xor(s, 1, 64);
            s += __shfl_xor(s, 2, 64);
            s += __shfl_xor(s, 4, 64);
            s += __shfl_xor(s, 8, 64);
            if (lm == 0)
                atomicAdd(&l[b * 4096 + it * 128 + wm + i * 16 + lg * 4 + r], s);
        }
}

// ---------------------------------------------------------------------------
// O = P @ V: 128 rows x 256 cols per block, grid 512, balance-aware mapping
// (CU pairs block g with g+256: it sums to 31 — constant K-work per CU).
// Direct store scaled by 1/l. No atomics.
// ---------------------------------------------------------------------------
__global__ __launch_bounds__(256, 2) void pv_gemm(const u16* __restrict__ P,
                                                  const u16* __restrict__ Vt,
                                                  const float* __restrict__ l,
                                                  float* __restrict__ Out) {
    __shared__ u16 sA[8192], sB[16384];
    int g  = blockIdx.x;
    int it = (g < 256) ? (31 - (g >> 4)) : ((g - 256) >> 4);
    int rem = g & 15;
    int b   = rem >> 2;
    int atp = rem & 3;

    const int t    = threadIdx.x;
    const int lane = t & 63;
    const int wave = t >> 6;
    const int wm   = (wave & 1) << 6;
    const int wn   = (wave >> 1) << 6;
    const int lm   = lane & 15;
    const int lg   = lane >> 4;
    const int sr   = t >> 3;
    const int sc   = (((t & 7) ^ ((t >> 3) & 7)) << 3);

    const u16* Pbase = P + (long)(b * 528 + ((it * (it + 1)) >> 1)) * 16384;
    const u16* gA0 = Pbase + sr * 128 + sc;
    const u16* gB0 = Vt + (long)b * 4194304 + (long)(atp * 256 + sr) * 4096 + sc;
    const u16* gC0 = gB0 + (long)128 * 4096;

    f32x4 acc0[4][4] = {}, acc1[4][4] = {};
    for (int jt = 0; jt <= it; jt++) {
        long aoff = (long)jt * 16384;
        long boff = (long)jt * 128;
#pragma unroll
        for (int kk = 0; kk < 128; kk += 64)
            kstep64(gA0 + aoff + kk, gB0 + boff + kk, gC0 + boff + kk,
                    128, 4096, sA, sB, wm, wn, lm, lg, acc0, acc1);
    }

#pragma unroll
    for (int i = 0; i < 4; i++)
#pragma unroll
        for (int r = 0; r < 4; r++) {
            int gi = it * 128 + wm + i * 16 + lg * 4 + r;
            float scale = 1.0f / l[b * 4096 + gi];
#pragma unroll
            for (int j = 0; j < 4; j++) {
                int ga = atp * 256 + wn + j * 16 + lm;
                float* o = &Out[((long)b * 4096 + gi) * 1024 + ga];
                o[0]   = acc0[i][j][r] * scale;
                o[128] = acc1[i][j][r] * scale;
            }
        }
}

// ---------------------------------------------------------------------------
// Workspace layout (bytes):
//   Qb   [0,          33554432)
//   Kb   [33554432,   67108864)
//   Vt   [67108864,  100663296)
//   l    [100663296, 100728832)   fp32 row sums (atomic-accumulated)
//   Xb   [100728832, 134283264)   (dead after proj_all8)
//   Wqt/Wkt/Wvt [134283264, 140574720)  (dead after proj_all8)
//   S/P  [100728832, 169934848)   packed tri tiles (bf16 P), overlays Xb+W
// ---------------------------------------------------------------------------
extern "C" void kernel_launch(void* const* d_in, const int* in_sizes, int n_in,
                              void* d_out, int out_size, void* d_ws, size_t ws_size,
                              hipStream_t stream) {
    const float* X  = (const float*)d_in[0];
    const float* Wk = (const float*)d_in[1];
    const float* Wq = (const float*)d_in[2];
    const float* Wv = (const float*)d_in[3];
    float* Out = (float*)d_out;

    char* w = (char*)d_ws;
    u16*   Qb   = (u16*)(w);
    u16*   Kb   = (u16*)(w + 33554432);
    u16*   Vt   = (u16*)(w + 67108864);
    float* l    = (float*)(w + 100663296);
    u16*   Xb   = (u16*)(w + 100728832);
    u16*   Wqt  = (u16*)(w + 134283264);
    u16*   Wkt  = (u16*)(w + 136380416);
    u16*   Wvt  = (u16*)(w + 138477568);
    u16*   S    = (u16*)(w + 100728832);

    hipMemsetAsync(l, 0, 65536, stream);
    convert_x<<<16384, 256, 0, stream>>>(X, Xb);
    convert_w<<<dim3(256, 3), 256, 0, stream>>>(Wk, Wq, Wv, Wkt, Wqt, Wvt);
    proj_all8<<<768, 512, 0, stream>>>(Xb, Wqt, Wkt, Wvt, Qb, Kb, Vt);
    sgemm_causal<<<1088, 256, 0, stream>>>(Qb, Kb, S, l);
    pv_gemm<<<512, 256, 0, stream>>>(S, Vt, l, Out);
}

// Round 2
// 415.652 us; speedup vs baseline: 1.0426x; 1.0269x over previous
//
#include <hip/hip_runtime.h>
#include <hip/hip_fp16.h>

typedef __attribute__((ext_vector_type(4))) float f32x4;
typedef __attribute__((ext_vector_type(8))) short s16x8;
typedef __attribute__((ext_vector_type(4))) short s16x4;
typedef unsigned short u16;
typedef unsigned int u32;

__device__ __forceinline__ u16 f2bf(float f) {
    union { float f; unsigned u; } x; x.f = f;
    return (u16)((x.u + 0x7fffu + ((x.u >> 16) & 1u)) >> 16);
}

__device__ __forceinline__ void ld16(const void* g, void* l) {
    __builtin_amdgcn_global_load_lds(
        (const __attribute__((address_space(1))) unsigned int*)g,
        (__attribute__((address_space(3))) unsigned int*)l, 16, 0, 0);
}

// ---------------------------------------------------------------------------
// BK=64 K-step of a 128x256 output tile (legacy 2-barrier core, still used by
// sgemm_causal and pv_gemm this round).
// ---------------------------------------------------------------------------
__device__ __forceinline__ void kstep64(const u16* gA, const u16* gB, const u16* gC,
                                        long lda, long ldb,
                                        u16* sA, u16* sB,
                                        int wm, int wn, int lm, int lg,
                                        f32x4 acc0[4][4], f32x4 acc1[4][4])
{
    const int t = threadIdx.x;
    __syncthreads();                 // previous iter's readers done
#pragma unroll
    for (int p = 0; p < 4; p++) {
        ld16(gA + (long)p * 32 * lda, sA + p * 2048 + t * 8);
        ld16(gB + (long)p * 32 * ldb, sB + p * 2048 + t * 8);
        ld16(gC + (long)p * 32 * ldb, sB + 8192 + p * 2048 + t * 8);
    }
    __syncthreads();                 // drains vmcnt for global_load_lds

#pragma unroll
    for (int s = 0; s < 2; s++) {
        s16x8 af[4], bf[4], cf[4];
        const int co = (((s * 4 + lg) ^ (lm & 7)) << 3);
#pragma unroll
        for (int i = 0; i < 4; i++) {
            af[i] = *(const s16x8*)&sA[(wm + i * 16 + lm) * 64 + co];
            bf[i] = *(const s16x8*)&sB[(wn + i * 16 + lm) * 64 + co];
            cf[i] = *(const s16x8*)&sB[8192 + (wn + i * 16 + lm) * 64 + co];
        }
#pragma unroll
        for (int i = 0; i < 4; i++)
#pragma unroll
            for (int j = 0; j < 4; j++) {
                acc0[i][j] = __builtin_amdgcn_mfma_f32_16x16x32_bf16(af[i], bf[j], acc0[i][j], 0, 0, 0);
                acc1[i][j] = __builtin_amdgcn_mfma_f32_16x16x32_bf16(af[i], cf[j], acc1[i][j], 0, 0, 0);
            }
    }
}

// Contiguous-K core: C[m][n] = sum_k A[m][k]*B[n][k] for n in two 128-tiles.
__device__ __forceinline__ void gemm_core64(const u16* A, long lda,
                                            const u16* B0, const u16* B1, long ldb,
                                            int m0, int kEnd,
                                            f32x4 acc0[4][4], f32x4 acc1[4][4],
                                            u16* sA, u16* sB)
{
    const int t    = threadIdx.x;
    const int lane = t & 63;
    const int wave = t >> 6;
    const int wm   = (wave & 1) << 6;
    const int wn   = (wave >> 1) << 6;
    const int lm   = lane & 15;
    const int lg   = lane >> 4;
    const int sr   = t >> 3;                              // staging row 0..31
    const int sc   = (((t & 7) ^ ((t >> 3) & 7)) << 3);   // swizzled chunk
    const u16* gA0 = A + (long)(m0 + sr) * lda + sc;
    const u16* gB0 = B0 + (long)sr * ldb + sc;
    const u16* gC0 = B1 + (long)sr * ldb + sc;

    for (int k0 = 0; k0 < kEnd; k0 += 64)
        kstep64(gA0 + k0, gB0 + k0, gC0 + k0, lda, ldb,
                sA, sB, wm, wn, lm, lg, acc0, acc1);
}

// ---------------------------------------------------------------------------
// Conversions
// ---------------------------------------------------------------------------
__global__ void convert_x(const float* __restrict__ X, u16* __restrict__ Xb) {
    long idx = ((long)blockIdx.x * 256 + threadIdx.x) * 4;
    f32x4 v = *(const f32x4*)&X[idx];
    s16x4 o;
    o.x = (short)f2bf(v.x); o.y = (short)f2bf(v.y);
    o.z = (short)f2bf(v.z); o.w = (short)f2bf(v.w);
    *(s16x4*)&Xb[idx] = o;
}

// W[k][n] fp32 -> Wt[n][k] bf16, 64x64 LDS tile transpose. grid (256, 3)
__global__ void convert_w(const float* __restrict__ Wk, const float* __restrict__ Wq,
                          const float* __restrict__ Wv,
                          u16* __restrict__ Wkt, u16* __restrict__ Wqt, u16* __restrict__ Wvt) {
    const float* W; u16* O;
    if (blockIdx.y == 0)      { W = Wk; O = Wkt; }
    else if (blockIdx.y == 1) { W = Wq; O = Wqt; }
    else                      { W = Wv; O = Wvt; }
    __shared__ u16 tile[64][65];
    int k0 = (blockIdx.x >> 4) << 6, n0 = (blockIdx.x & 15) << 6;
    int t = threadIdx.x;
    int rr = t >> 4, cc = (t & 15) << 2;
#pragma unroll
    for (int i = 0; i < 4; i++) {
        int row = rr + i * 16;
        f32x4 v = *(const f32x4*)&W[(long)(k0 + row) * 1024 + n0 + cc];
        tile[row][cc + 0] = f2bf(v.x); tile[row][cc + 1] = f2bf(v.y);
        tile[row][cc + 2] = f2bf(v.z); tile[row][cc + 3] = f2bf(v.w);
    }
    __syncthreads();
#pragma unroll
    for (int i = 0; i < 4; i++) {
        int row = rr + i * 16;
        s16x4 pk;
        pk.x = (short)tile[cc + 0][row]; pk.y = (short)tile[cc + 1][row];
        pk.z = (short)tile[cc + 2][row]; pk.w = (short)tile[cc + 3][row];
        *(s16x4*)&O[(long)(n0 + row) * 1024 + k0 + cc] = pk;
    }
}

// ---------------------------------------------------------------------------
// 8-phase 256x256 projection GEMM, overlap-fixed (R2).
// Key change vs R1: NO explicit lgkmcnt(0) drains — fragment reads are plain
// compiler loads with register deps into the MFMAs, so hipcc emits counted
// lgkmcnt(N) per use; late ds_reads get serviced UNDER earlier MFMAs instead
// of serializing (R1 measured sum-of-pipes = 9.5k cyc/iter; overlap target
// ~= max + eps). Reads redistributed so each phase's reads are consumed
// in-phase: ph+0: A-lo(8)+B01(4); ph+1: B23(4); ph+2: A-hi(8); ph+3: none.
//
// Stage stream (E=2it in sA0/sB0 @ph0-3, O=2it+1 in sA1/sB1 @ph4-7):
//   ph0: O.A h0   ph1: O.A h1   ph2: E'.B h0  ph3: E'.B h1
//   ph4: E'.A h0  ph5: E'.A h1  ph6: O'.B h0  ph7: O'.B h1
// Slot-safety: every phase's reads are consumed by that phase's MFMAs
// (compiler counted waits), which precede the end-of-phase barrier; each
// stage targets a slot whose last read-phase ended >=1 barrier earlier:
//   sB0 last read ph1 -> staged ph2/3; sA0 last read ph2 -> staged ph4/5;
//   sB1 last read ph5 -> staged ph6/7; sA1 last read ph6 -> staged ph0/1.
// Read/write slots within a phase are always disjoint (checked per phase).
// vmcnt: per-wave 2 loads/phase. At ph3, outstanding <= 12 (leftover E'.B<=4
// + ph0..3 = 8); vmcnt(4) leaves only ph2/3 (E'.B) -> O tile fully staged.
// At ph7, vmcnt(4) leaves only ph6/7 (O'.B) -> E' fully staged before next
// ph0. Tail (it=7): ph3 waits vmcnt(0) (only O.A outstanding), no later waits.
// Prologue: E0.B, E0.A, O0.B (12 loads), vmcnt(4) -> E0 complete.
// ---------------------------------------------------------------------------
__device__ __forceinline__ void stage_half64(const u16* gbase, u16* lbase,
                                             int kt, int h, int t) {
    const u16* g = gbase + (long)(h * 128) * 1024 + kt * 64;
    u16* l = lbase + h * 8192 + t * 8;
    ld16(g, l);
    ld16(g + 64 * 1024, l + 4096);
}

__device__ __forceinline__ void read_A8(const u16* sA, int arow, int ih,
                                        int co0, int co1, s16x8 af[4][2]) {
#pragma unroll
    for (int i = 0; i < 4; i++) {
        af[i][0] = *(const s16x8*)&sA[(arow + (ih * 4 + i) * 16) * 64 + co0];
        af[i][1] = *(const s16x8*)&sA[(arow + (ih * 4 + i) * 16) * 64 + co1];
    }
}

__device__ __forceinline__ void read_B4(const u16* sB, int brow, int jp,
                                        int co0, int co1, s16x8 bf[4][2]) {
#pragma unroll
    for (int j = 2 * jp; j < 2 * jp + 2; j++) {
        bf[j][0] = *(const s16x8*)&sB[(brow + j * 16) * 64 + co0];
        bf[j][1] = *(const s16x8*)&sB[(brow + j * 16) * 64 + co1];
    }
}

__device__ __forceinline__ void mfma16q(f32x4 acc[8][4], const s16x8 af[4][2],
                                        const s16x8 bf[4][2], int ih, int jh) {
    __builtin_amdgcn_s_setprio(1);
#pragma unroll
    for (int i = 0; i < 4; i++)
#pragma unroll
        for (int j = 0; j < 2; j++)
#pragma unroll
            for (int s = 0; s < 2; s++)
                acc[ih * 4 + i][jh * 2 + j] = __builtin_amdgcn_mfma_f32_16x16x32_bf16(
                    af[i][s], bf[jh * 2 + j][s], acc[ih * 4 + i][jh * 2 + j], 0, 0, 0);
    __builtin_amdgcn_s_setprio(0);
}

// raw barrier: ordering fence for memory ops WITHOUT a forced waitcnt drain
#define ABAR() asm volatile("s_barrier" ::: "memory")

__global__ __launch_bounds__(512, 2) void proj_all8(const u16* __restrict__ X,
                                                    const u16* __restrict__ Wqt,
                                                    const u16* __restrict__ Wkt,
                                                    const u16* __restrict__ Wvt,
                                                    u16* __restrict__ Qb,
                                                    u16* __restrict__ Kb,
                                                    u16* __restrict__ Vt) {
    __shared__ u16 lds[65536];                   // 128 KiB: A bufs then B bufs
    // XCD-chunked bijective swizzle: 768 blocks = 8 XCDs x 96; consecutive
    // origs (which share the A panel) stay on one XCD's L2.
    const int bx  = ((blockIdx.x & 7) * 96) + (blockIdx.x >> 3);
    const int z   = bx >> 8;                     // 0:Q 1:K 2:V
    const int rem = bx & 255;
    const int m0  = (rem >> 2) << 8;
    const int n0  = (rem & 3) << 8;
    const u16* Wt = (z == 0) ? Wqt : (z == 1) ? Wkt : Wvt;

    const int t  = threadIdx.x;
    const int sr = t >> 3;                       // staging row 0..63
    const int sc = ((t & 7) ^ (sr & 7)) << 3;    // swizzled 16B chunk (u16 units)
    const u16* Ast = X  + (long)(m0 + sr) * 1024 + sc;
    const u16* Bst = Wt + (long)(n0 + sr) * 1024 + sc;
    u16* sA0 = lds;
    u16* sA1 = lds + 16384;
    u16* sB0 = lds + 32768;
    u16* sB1 = lds + 49152;

    const int lane = t & 63, w = t >> 6;
    const int wr = w >> 2, wc = w & 3;           // 2M x 4N wave grid
    const int lm = lane & 15, lg = lane >> 4;
    const int arow = wr * 128 + lm;
    const int brow = wc * 64 + lm;
    const int co0 = ((lg) ^ (lm & 7)) << 3;      // k-chunk for s=0 (swizzled)
    const int co1 = ((4 + lg) ^ (lm & 7)) << 3;  // k-chunk for s=1

    f32x4 acc[8][4] = {};
    s16x8 af[4][2], bf[4][2];

    // Prologue: E0.B, E0.A, O0.B (12 loads); vmcnt(4) -> E0 fully staged,
    // O0.B (4 loads) still in flight.
    stage_half64(Bst, sB0, 0, 0, t); stage_half64(Bst, sB0, 0, 1, t);
    stage_half64(Ast, sA0, 0, 0, t); stage_half64(Ast, sA0, 0, 1, t);
    stage_half64(Bst, sB1, 1, 0, t); stage_half64(Bst, sB1, 1, 1, t);
    asm volatile("s_waitcnt vmcnt(4)" ::: "memory");
    ABAR();

#pragma unroll 1
    for (int it = 0; it < 8; it++) {
        const int  tO   = 2 * it + 1;
        const bool more = (it < 7);
        // ---- phase 0: E q(0,0); reads A-lo + B01; stage O.A h0
        read_A8(sA0, arow, 0, co0, co1, af);
        read_B4(sB0, brow, 0, co0, co1, bf);
        stage_half64(Ast, sA1, tO, 0, t);
        ABAR();
        mfma16q(acc, af, bf, 0, 0);
        ABAR();
        // ---- phase 1: E q(0,1); reads B23; stage O.A h1
        read_B4(sB0, brow, 1, co0, co1, bf);
        stage_half64(Ast, sA1, tO, 1, t);
        ABAR();
        mfma16q(acc, af, bf, 0, 1);
        ABAR();
        // ---- phase 2: E q(1,0); reads A-hi; stage E'.B h0
        read_A8(sA0, arow, 1, co0, co1, af);
        if (more) stage_half64(Bst, sB0, tO + 1, 0, t);
        ABAR();
        mfma16q(acc, af, bf, 1, 0);
        ABAR();
        // ---- phase 3: E q(1,1); stage E'.B h1; counted vmcnt (O fully staged)
        if (more) stage_half64(Bst, sB0, tO + 1, 1, t);
        ABAR();
        mfma16q(acc, af, bf, 1, 1);
        if (more) asm volatile("s_waitcnt vmcnt(4)" ::: "memory");
        else      asm volatile("s_waitcnt vmcnt(0)" ::: "memory");
        ABAR();
        // ---- phase 4: O q(0,0); reads A-lo + B01; stage E'.A h0
        read_A8(sA1, arow, 0, co0, co1, af);
        read_B4(sB1, brow, 0, co0, co1, bf);
        if (more) stage_half64(Ast, sA0, tO + 1, 0, t);
        ABAR();
        mfma16q(acc, af, bf, 0, 0);
        ABAR();
        // ---- phase 5: O q(0,1); reads B23; stage E'.A h1
        read_B4(sB1, brow, 1, co0, co1, bf);
        if (more) stage_half64(Ast, sA0, tO + 1, 1, t);
        ABAR();
        mfma16q(acc, af, bf, 0, 1);
        ABAR();
        // ---- phase 6: O q(1,0); reads A-hi; stage O'.B h0
        read_A8(sA1, arow, 1, co0, co1, af);
        if (more) stage_half64(Bst, sB1, tO + 2, 0, t);
        ABAR();
        mfma16q(acc, af, bf, 1, 0);
        ABAR();
        // ---- phase 7: O q(1,1); stage O'.B h1; counted vmcnt (E' staged)
        if (more) stage_half64(Bst, sB1, tO + 2, 1, t);
        ABAR();
        mfma16q(acc, af, bf, 1, 1);
        if (more) asm volatile("s_waitcnt vmcnt(4)" ::: "memory");
        ABAR();
    }

    // Epilogue: rows m0 + wr*128 + i*16 + lg*4 + r ; cols n0 + wc*64 + j*16 + lm
    if (z < 2) {
        u16* O = (z == 0) ? Qb : Kb;
#pragma unroll
        for (int i = 0; i < 8; i++)
#pragma unroll
            for (int j = 0; j < 4; j++)
#pragma unroll
                for (int r = 0; r < 4; r++) {
                    int row = m0 + wr * 128 + i * 16 + lg * 4 + r;
                    int col = n0 + wc * 64 + j * 16 + lm;
                    O[(long)row * 1024 + col] = f2bf(acc[i][j][r]);
                }
    } else {
#pragma unroll
        for (int i = 0; i < 8; i++)
#pragma unroll
            for (int j = 0; j < 4; j++) {
                int row0 = m0 + wr * 128 + i * 16 + lg * 4;
                int col  = n0 + wc * 64 + j * 16 + lm;
                int b = row0 >> 12, s = row0 & 4095;
                s16x4 p0;
                p0.x = (short)f2bf(acc[i][j][0]); p0.y = (short)f2bf(acc[i][j][1]);
                p0.z = (short)f2bf(acc[i][j][2]); p0.w = (short)f2bf(acc[i][j][3]);
                *(s16x4*)&Vt[(long)b * 4194304 + (long)col * 4096 + s] = p0;
            }
    }
}

// ---------------------------------------------------------------------------
// Fused S-GEMM + softmax-numerator: P = exp(QK^T/32 - 16) (causal; fixed
// offset replaces the row max — scale-invariant, cancels in p/l). P written
// bf16 into packed lower-tri tiles; per-row sums accumulated into l[] via
// 16-lane shuffle reduction + one atomicAdd per row-quarter. grid 4*272.
// ---------------------------------------------------------------------------
__global__ __launch_bounds__(256, 2) void sgemm_causal(const u16* __restrict__ Q,
                                                       const u16* __restrict__ K,
                                                       u16* __restrict__ S,
                                                       float* __restrict__ l) {
    __shared__ u16 sA[8192], sB[16384];
    int b  = blockIdx.x / 272;
    int tt = blockIdx.x % 272;
    int it = (int)(2.0f * sqrtf((float)tt + 1.0f)) - 1;
    if (it > 31) it = 31;
    if (it < 0) it = 0;
    while (it < 31 && (((it + 2) * (it + 2)) >> 2) <= tt) ++it;
    while (it > 0 && (((it + 1) * (it + 1)) >> 2) > tt) --it;
    int jp  = tt - (((it + 1) * (it + 1)) >> 2);
    int jt0 = jp * 2, jt1 = jt0 + 1;
    bool valid1 = (jt1 <= it);

    const u16* A  = Q + (long)b * 4194304;
    const u16* Kp = K + (long)b * 4194304;
    f32x4 acc0[4][4] = {}, acc1[4][4] = {};
    gemm_core64(A, 1024, Kp + (long)jt0 * 131072, Kp + (long)jt1 * 131072, 1024,
                it * 128, 1024, acc0, acc1, sA, sB);

    long tribase = (long)(b * 528 + ((it * (it + 1)) >> 1));
    u16* Sp0 = S + (tribase + jt0) * 16384;
    u16* Sp1 = S + (tribase + jt1) * 16384;
    int lane = threadIdx.x & 63, wave = threadIdx.x >> 6;
    int wm = (wave & 1) << 6, wn = (wave >> 1) << 6, lm = lane & 15, lg = lane >> 4;
    const float LOG2E = 1.44269504088896f;

    float rs[4][4];
#pragma unroll
    for (int i = 0; i < 4; i++)
#pragma unroll
        for (int r = 0; r < 4; r++) rs[i][r] = 0.0f;

#pragma unroll
    for (int i = 0; i < 4; i++)
#pragma unroll
        for (int j = 0; j < 4; j++)
#pragma unroll
            for (int r = 0; r < 4; r++) {
                int ri = wm + i * 16 + lg * 4 + r;
                int cj = wn + j * 16 + lm;
                int gi = it * 128 + ri;
                float p0 = (jt0 * 128 + cj > gi) ? 0.0f
                         : exp2f((acc0[i][j][r] * 0.03125f - 16.0f) * LOG2E);
                Sp0[ri * 128 + cj] = f2bf(p0);
                rs[i][r] += p0;
                if (valid1) {
                    float p1 = (jt1 * 128 + cj > gi) ? 0.0f
                             : exp2f((acc1[i][j][r] * 0.03125f - 16.0f) * LOG2E);
                    Sp1[ri * 128 + cj] = f2bf(p1);
                    rs[i][r] += p1;
                }
            }

#pragma unroll
    for (int i = 0; i < 4; i++)
#pragma unroll
        for (int r = 0; r < 4; r++) {
            float s = rs[i][r];
            s += __shfl_xor(s, 1, 64);
            s += __shfl_xor(s, 2, 64);
            s += __shfl_xor(s, 4, 64);
            s += __shfl_xor(s, 8, 64);
            if (lm == 0)
                atomicAdd(&l[b * 4096 + it * 128 + wm + i * 16 + lg * 4 + r], s);
        }
}

// ---------------------------------------------------------------------------
// O = P @ V: 128 rows x 256 cols per block, grid 512, balance-aware mapping
// (CU pairs block g with g+256: it sums to 31 — constant K-work per CU).
// Direct store scaled by 1/l. No atomics.
// ---------------------------------------------------------------------------
__global__ __launch_bounds__(256, 2) void pv_gemm(const u16* __restrict__ P,
                                                  const u16* __restrict__ Vt,
                                                  const float* __restrict__ l,
                                                  float* __restrict__ Out) {
    __shared__ u16 sA[8192], sB[16384];
    int g  = blockIdx.x;
    int it = (g < 256) ? (31 - (g >> 4)) : ((g - 256) >> 4);
    int rem = g & 15;
    int b   = rem >> 2;
    int atp = rem & 3;

    const int t    = threadIdx.x;
    const int lane = t & 63;
    const int wave = t >> 6;
    const int wm   = (wave & 1) << 6;
    const int wn   = (wave >> 1) << 6;
    const int lm   = lane & 15;
    const int lg   = lane >> 4;
    const int sr   = t >> 3;
    const int sc   = (((t & 7) ^ ((t >> 3) & 7)) << 3);

    const u16* Pbase = P + (long)(b * 528 + ((it * (it + 1)) >> 1)) * 16384;
    const u16* gA0 = Pbase + sr * 128 + sc;
    const u16* gB0 = Vt + (long)b * 4194304 + (long)(atp * 256 + sr) * 4096 + sc;
    const u16* gC0 = gB0 + (long)128 * 4096;

    f32x4 acc0[4][4] = {}, acc1[4][4] = {};
    for (int jt = 0; jt <= it; jt++) {
        long aoff = (long)jt * 16384;
        long boff = (long)jt * 128;
#pragma unroll
        for (int kk = 0; kk < 128; kk += 64)
            kstep64(gA0 + aoff + kk, gB0 + boff + kk, gC0 + boff + kk,
                    128, 4096, sA, sB, wm, wn, lm, lg, acc0, acc1);
    }

#pragma unroll
    for (int i = 0; i < 4; i++)
#pragma unroll
        for (int r = 0; r < 4; r++) {
            int gi = it * 128 + wm + i * 16 + lg * 4 + r;
            float scale = 1.0f / l[b * 4096 + gi];
#pragma unroll
            for (int j = 0; j < 4; j++) {
                int ga = atp * 256 + wn + j * 16 + lm;
                float* o = &Out[((long)b * 4096 + gi) * 1024 + ga];
                o[0]   = acc0[i][j][r] * scale;
                o[128] = acc1[i][j][r] * scale;
            }
        }
}

// ---------------------------------------------------------------------------
// Workspace layout (bytes):
//   Qb   [0,          33554432)
//   Kb   [33554432,   67108864)
//   Vt   [67108864,  100663296)
//   l    [100663296, 100728832)   fp32 row sums (atomic-accumulated)
//   Xb   [100728832, 134283264)   (dead after proj_all8)
//   Wqt/Wkt/Wvt [134283264, 140574720)  (dead after proj_all8)
//   S/P  [100728832, 169934848)   packed tri tiles (bf16 P), overlays Xb+W
// ---------------------------------------------------------------------------
extern "C" void kernel_launch(void* const* d_in, const int* in_sizes, int n_in,
                              void* d_out, int out_size, void* d_ws, size_t ws_size,
                              hipStream_t stream) {
    const float* X  = (const float*)d_in[0];
    const float* Wk = (const float*)d_in[1];
    const float* Wq = (const float*)d_in[2];
    const float* Wv = (const float*)d_in[3];
    float* Out = (float*)d_out;

    char* w = (char*)d_ws;
    u16*   Qb   = (u16*)(w);
    u16*   Kb   = (u16*)(w + 33554432);
    u16*   Vt   = (u16*)(w + 67108864);
    float* l    = (float*)(w + 100663296);
    u16*   Xb   = (u16*)(w + 100728832);
    u16*   Wqt  = (u16*)(w + 134283264);
    u16*   Wkt  = (u16*)(w + 136380416);
    u16*   Wvt  = (u16*)(w + 138477568);
    u16*   S    = (u16*)(w + 100728832);

    hipMemsetAsync(l, 0, 65536, stream);
    convert_x<<<16384, 256, 0, stream>>>(X, Xb);
    convert_w<<<dim3(256, 3), 256, 0, stream>>>(Wk, Wq, Wv, Wkt, Wqt, Wvt);
    proj_all8<<<768, 512, 0, stream>>>(Xb, Wqt, Wkt, Wvt, Qb, Kb, Vt);
    sgemm_causal<<<1088, 256, 0, stream>>>(Qb, Kb, S, l);
    pv_gemm<<<512, 256, 0, stream>>>(S, Vt, l, Out);
}